// Round 1
// baseline (684.826 us; speedup 1.0000x reference)
//
#include <hip/hip_runtime.h>

#define LOG2E 1.44269504088896340736f

__device__ __forceinline__ float fexp2(float x) { return __builtin_amdgcn_exp2f(x); }
__device__ __forceinline__ float frcp(float x)  { return __builtin_amdgcn_rcpf(x); }

__device__ __forceinline__ float sigmoid_f(float x) {
    // 1/(1+exp(-x)) = rcp(1 + 2^(-x*log2e))
    return frcp(1.0f + fexp2(-x * LOG2E));
}
__device__ __forceinline__ float tanh_f(float x) {
    // (t-1)/(t+1), t = exp(2x) = 2^(2x*log2e)
    float t = fexp2(x * (2.0f * LOG2E));
    return (t - 1.0f) * frcp(t + 1.0f);
}

// One LSTM cell step. DIN = input dim. Weights/biases are wave-uniform ->
// compiler scalarizes loads into s_load + SGPR-operand v_fmac.
template <int DIN>
__device__ __forceinline__ void lstm_cell(const float* __restrict__ Wih,   // 64 x DIN
                                          const float* __restrict__ Whh,   // 64 x 16
                                          const float* __restrict__ bih,   // 64
                                          const float* __restrict__ bhh,   // 64
                                          const float (&x)[DIN],
                                          const float (&hin)[16],
                                          float (&c)[16],
                                          float (&hout)[16]) {
#pragma unroll
    for (int j = 0; j < 16; ++j) {
        float gi = bih[j]      + bhh[j];
        float gf = bih[16 + j] + bhh[16 + j];
        float gg = bih[32 + j] + bhh[32 + j];
        float go = bih[48 + j] + bhh[48 + j];
#pragma unroll
        for (int k = 0; k < DIN; ++k) {
            gi += Wih[j * DIN + k]        * x[k];
            gf += Wih[(16 + j) * DIN + k] * x[k];
            gg += Wih[(32 + j) * DIN + k] * x[k];
            go += Wih[(48 + j) * DIN + k] * x[k];
        }
#pragma unroll
        for (int k = 0; k < 16; ++k) {
            gi += Whh[j * 16 + k]        * hin[k];
            gf += Whh[(16 + j) * 16 + k] * hin[k];
            gg += Whh[(32 + j) * 16 + k] * hin[k];
            go += Whh[(48 + j) * 16 + k] * hin[k];
        }
        float i_ = sigmoid_f(gi);
        float f_ = sigmoid_f(gf);
        float g_ = tanh_f(gg);
        float o_ = sigmoid_f(go);
        float cn = f_ * c[j] + i_ * g_;
        c[j] = cn;
        hout[j] = o_ * tanh_f(cn);
    }
}

__global__ __launch_bounds__(256, 4)
void lstm_fused_kernel(const float* __restrict__ in,     // B x 8 x 8
                       const float* __restrict__ Wih0,   // 64 x 8
                       const float* __restrict__ Whh0,   // 64 x 16
                       const float* __restrict__ bih0,
                       const float* __restrict__ bhh0,
                       const float* __restrict__ Wih1,   // 64 x 16
                       const float* __restrict__ Whh1,   // 64 x 16
                       const float* __restrict__ bih1,
                       const float* __restrict__ bhh1,
                       const float* __restrict__ Wfc,    // 10 x 16
                       const float* __restrict__ bfc,    // 10
                       float* __restrict__ out,          // B x 10
                       int B) {
    int b = blockIdx.x * blockDim.x + threadIdx.x;
    if (b >= B) return;

    const float* xin = in + (size_t)b * 64;

    float h0[16], c0[16], h1[16], c1[16];
#pragma unroll
    for (int j = 0; j < 16; ++j) { h0[j] = 0.f; c0[j] = 0.f; h1[j] = 0.f; c1[j] = 0.f; }

    for (int t = 0; t < 8; ++t) {
        // load x_t: 8 contiguous, 32B-aligned floats
        float x[8];
        const float4* xp = (const float4*)(xin + t * 8);
        float4 a0 = xp[0];
        float4 a1 = xp[1];
        x[0] = a0.x; x[1] = a0.y; x[2] = a0.z; x[3] = a0.w;
        x[4] = a1.x; x[5] = a1.y; x[6] = a1.z; x[7] = a1.w;

        // layer 0: h0,c0 -> nh
        float nh[16];
        lstm_cell<8>(Wih0, Whh0, bih0, bhh0, x, h0, c0, nh);
#pragma unroll
        for (int j = 0; j < 16; ++j) h0[j] = nh[j];   // h0 now = layer-0 output at t

        // layer 1: input = h0 (new), state h1,c1 -> nh1
        float nh1[16];
        lstm_cell<16>(Wih1, Whh1, bih1, bhh1, h0, h1, c1, nh1);
#pragma unroll
        for (int j = 0; j < 16; ++j) h1[j] = nh1[j];
    }

    // FC on last h1
    float* op = out + (size_t)b * 10;
#pragma unroll
    for (int ci = 0; ci < 10; ++ci) {
        float acc = bfc[ci];
#pragma unroll
        for (int k = 0; k < 16; ++k) acc += Wfc[ci * 16 + k] * h1[k];
        op[ci] = acc;
    }
}

extern "C" void kernel_launch(void* const* d_in, const int* in_sizes, int n_in,
                              void* d_out, int out_size, void* d_ws, size_t ws_size,
                              hipStream_t stream) {
    const float* in   = (const float*)d_in[0];
    const float* Wih0 = (const float*)d_in[1];
    const float* Whh0 = (const float*)d_in[2];
    const float* bih0 = (const float*)d_in[3];
    const float* bhh0 = (const float*)d_in[4];
    const float* Wih1 = (const float*)d_in[5];
    const float* Whh1 = (const float*)d_in[6];
    const float* bih1 = (const float*)d_in[7];
    const float* bhh1 = (const float*)d_in[8];
    const float* Wfc  = (const float*)d_in[9];
    const float* bfc  = (const float*)d_in[10];
    float* out = (float*)d_out;

    int B = in_sizes[0] / 64;   // 262144
    int block = 256;
    int grid = (B + block - 1) / block;
    lstm_fused_kernel<<<grid, block, 0, stream>>>(in, Wih0, Whh0, bih0, bhh0,
                                                  Wih1, Whh1, bih1, bhh1,
                                                  Wfc, bfc, out, B);
}

// Round 2
// 674.498 us; speedup vs baseline: 1.0153x; 1.0153x over previous
//
#include <hip/hip_runtime.h>

#define LOG2E 1.44269504088896340736f

__device__ __forceinline__ float fexp2(float x) { return __builtin_amdgcn_exp2f(x); }
__device__ __forceinline__ float frcp(float x)  { return __builtin_amdgcn_rcpf(x); }

__device__ __forceinline__ float sigmoid_f(float x) {
    return frcp(1.0f + fexp2(-x * LOG2E));
}
__device__ __forceinline__ float tanh_f(float x) {
    float t = fexp2(x * (2.0f * LOG2E));
    return (t - 1.0f) * frcp(t + 1.0f);
}

// One LSTM cell step. Weights/biases are wave-uniform -> scalar loads,
// v_fmac_f32 with SGPR weight operand.
template <int DIN>
__device__ __forceinline__ void lstm_cell(const float* __restrict__ Wih,   // 64 x DIN
                                          const float* __restrict__ Whh,   // 64 x 16
                                          const float* __restrict__ bih,   // 64
                                          const float* __restrict__ bhh,   // 64
                                          const float (&x)[DIN],
                                          const float (&hin)[16],
                                          float (&c)[16],
                                          float (&hout)[16]) {
#pragma unroll
    for (int j = 0; j < 16; ++j) {
        float gi = bih[j]      + bhh[j];
        float gf = bih[16 + j] + bhh[16 + j];
        float gg = bih[32 + j] + bhh[32 + j];
        float go = bih[48 + j] + bhh[48 + j];
#pragma unroll
        for (int k = 0; k < DIN; ++k) {
            gi += Wih[j * DIN + k]        * x[k];
            gf += Wih[(16 + j) * DIN + k] * x[k];
            gg += Wih[(32 + j) * DIN + k] * x[k];
            go += Wih[(48 + j) * DIN + k] * x[k];
        }
#pragma unroll
        for (int k = 0; k < 16; ++k) {
            gi += Whh[j * 16 + k]        * hin[k];
            gf += Whh[(16 + j) * 16 + k] * hin[k];
            gg += Whh[(32 + j) * 16 + k] * hin[k];
            go += Whh[(48 + j) * 16 + k] * hin[k];
        }
        float i_ = sigmoid_f(gi);
        float f_ = sigmoid_f(gf);
        float g_ = tanh_f(gg);
        float o_ = sigmoid_f(go);
        float cn = f_ * c[j] + i_ * g_;
        c[j] = cn;
        hout[j] = o_ * tanh_f(cn);
    }
}

// min-waves-per-EU = 2 -> VGPR budget 256: the ~130 live floats (state +
// preloaded input) fit with NO scratch spills. Grid supplies ~4 waves/SIMD.
__global__ __launch_bounds__(256, 2)
void lstm_fused_kernel(const float* __restrict__ in,     // B x 8 x 8
                       const float* __restrict__ Wih0,   // 64 x 8
                       const float* __restrict__ Whh0,   // 64 x 16
                       const float* __restrict__ bih0,
                       const float* __restrict__ bhh0,
                       const float* __restrict__ Wih1,   // 64 x 16
                       const float* __restrict__ Whh1,   // 64 x 16
                       const float* __restrict__ bih1,
                       const float* __restrict__ bhh1,
                       const float* __restrict__ Wfc,    // 10 x 16
                       const float* __restrict__ bfc,    // 10
                       float* __restrict__ out,          // B x 10
                       int B) {
    int b = blockIdx.x * blockDim.x + threadIdx.x;
    if (b >= B) return;

    // Preload the whole 256B sample once: 16 back-to-back dwordx4 loads.
    // Consecutive lines fully consumed immediately -> FETCH == input size.
    float x[64];
    {
        const float4* xp = (const float4*)(in + (size_t)b * 64);
#pragma unroll
        for (int q = 0; q < 16; ++q) {
            float4 a = xp[q];
            x[q * 4 + 0] = a.x; x[q * 4 + 1] = a.y;
            x[q * 4 + 2] = a.z; x[q * 4 + 3] = a.w;
        }
    }

    float h0[16], c0[16], h1[16], c1[16];
#pragma unroll
    for (int j = 0; j < 16; ++j) { h0[j] = 0.f; c0[j] = 0.f; h1[j] = 0.f; c1[j] = 0.f; }

#pragma unroll
    for (int t = 0; t < 8; ++t) {
        float xt[8];
#pragma unroll
        for (int k = 0; k < 8; ++k) xt[k] = x[t * 8 + k];

        // layer 0
        float nh[16];
        lstm_cell<8>(Wih0, Whh0, bih0, bhh0, xt, h0, c0, nh);
#pragma unroll
        for (int j = 0; j < 16; ++j) h0[j] = nh[j];

        // layer 1 (consumes fresh h0)
        float nh1[16];
        lstm_cell<16>(Wih1, Whh1, bih1, bhh1, h0, h1, c1, nh1);
#pragma unroll
        for (int j = 0; j < 16; ++j) h1[j] = nh1[j];
    }

    // FC on last h1: 10 outputs, contiguous 40B per thread (coalesced
    // across the wave).
    float r[10];
#pragma unroll
    for (int ci = 0; ci < 10; ++ci) {
        float acc = bfc[ci];
#pragma unroll
        for (int k = 0; k < 16; ++k) acc += Wfc[ci * 16 + k] * h1[k];
        r[ci] = acc;
    }
    float* op = out + (size_t)b * 10;
#pragma unroll
    for (int ci = 0; ci < 10; ++ci) op[ci] = r[ci];
}

extern "C" void kernel_launch(void* const* d_in, const int* in_sizes, int n_in,
                              void* d_out, int out_size, void* d_ws, size_t ws_size,
                              hipStream_t stream) {
    const float* in   = (const float*)d_in[0];
    const float* Wih0 = (const float*)d_in[1];
    const float* Whh0 = (const float*)d_in[2];
    const float* bih0 = (const float*)d_in[3];
    const float* bhh0 = (const float*)d_in[4];
    const float* Wih1 = (const float*)d_in[5];
    const float* Whh1 = (const float*)d_in[6];
    const float* bih1 = (const float*)d_in[7];
    const float* bhh1 = (const float*)d_in[8];
    const float* Wfc  = (const float*)d_in[9];
    const float* bfc  = (const float*)d_in[10];
    float* out = (float*)d_out;

    int B = in_sizes[0] / 64;   // 262144
    int block = 256;
    int grid = (B + block - 1) / block;
    lstm_fused_kernel<<<grid, block, 0, stream>>>(in, Wih0, Whh0, bih0, bhh0,
                                                  Wih1, Whh1, bih1, bhh1,
                                                  Wfc, bfc, out, B);
}

// Round 3
// 671.373 us; speedup vs baseline: 1.0200x; 1.0047x over previous
//
#include <hip/hip_runtime.h>

#define LOG2E 1.44269504088896340736f

__device__ __forceinline__ float fexp2(float x) { return __builtin_amdgcn_exp2f(x); }
__device__ __forceinline__ float frcp(float x)  { return __builtin_amdgcn_rcpf(x); }

__device__ __forceinline__ float sigmoid_f(float x) {
    return frcp(1.0f + fexp2(-x * LOG2E));
}
__device__ __forceinline__ float tanh_f(float x) {
    float t = fexp2(x * (2.0f * LOG2E));
    return (t - 1.0f) * frcp(t + 1.0f);
}

// One LSTM cell step. Weights/biases are wave-uniform -> scalar loads,
// v_fmac_f32 with SGPR weight operand (doesn't consume the 1-SGPR-per-VALU
// budget beyond the weight itself).
template <int DIN>
__device__ __forceinline__ void lstm_cell(const float* __restrict__ Wih,   // 64 x DIN
                                          const float* __restrict__ Whh,   // 64 x 16
                                          const float* __restrict__ bih,   // 64
                                          const float* __restrict__ bhh,   // 64
                                          const float (&x)[DIN],
                                          const float (&hin)[16],
                                          float (&c)[16],
                                          float (&hout)[16]) {
#pragma unroll
    for (int j = 0; j < 16; ++j) {
        float gi = bih[j]      + bhh[j];
        float gf = bih[16 + j] + bhh[16 + j];
        float gg = bih[32 + j] + bhh[32 + j];
        float go = bih[48 + j] + bhh[48 + j];
#pragma unroll
        for (int k = 0; k < DIN; ++k) {
            gi += Wih[j * DIN + k]        * x[k];
            gf += Wih[(16 + j) * DIN + k] * x[k];
            gg += Wih[(32 + j) * DIN + k] * x[k];
            go += Wih[(48 + j) * DIN + k] * x[k];
        }
#pragma unroll
        for (int k = 0; k < 16; ++k) {
            gi += Whh[j * 16 + k]        * hin[k];
            gf += Whh[(16 + j) * 16 + k] * hin[k];
            gg += Whh[(32 + j) * 16 + k] * hin[k];
            go += Whh[(48 + j) * 16 + k] * hin[k];
        }
        float i_ = sigmoid_f(gi);
        float f_ = sigmoid_f(gf);
        float g_ = tanh_f(gg);
        float o_ = sigmoid_f(go);
        float cn = f_ * c[j] + i_ * g_;
        c[j] = cn;
        hout[j] = o_ * tanh_f(cn);
    }
}

// waves_per_eu(2,2): PIN the allocator's occupancy target at exactly 2
// waves/EU -> full 256-VGPR budget, no spill-to-reach-4-waves heuristic
// (round 2: VGPR=120 with 127 dwords/thread of scratch traffic).
__global__
__attribute__((amdgpu_flat_work_group_size(256, 256)))
__attribute__((amdgpu_waves_per_eu(2, 2)))
void lstm_fused_kernel(const float* __restrict__ in,     // B x 8 x 8
                       const float* __restrict__ Wih0,   // 64 x 8
                       const float* __restrict__ Whh0,   // 64 x 16
                       const float* __restrict__ bih0,
                       const float* __restrict__ bhh0,
                       const float* __restrict__ Wih1,   // 64 x 16
                       const float* __restrict__ Whh1,   // 64 x 16
                       const float* __restrict__ bih1,
                       const float* __restrict__ bhh1,
                       const float* __restrict__ Wfc,    // 10 x 16
                       const float* __restrict__ bfc,    // 10
                       float* __restrict__ out,          // B x 10
                       int B) {
    int b = blockIdx.x * blockDim.x + threadIdx.x;
    if (b >= B) return;

    // Preload the whole 256B sample once: 16 back-to-back dwordx4 loads,
    // lines fully consumed -> FETCH == input footprint, no refetch.
    float x[64];
    {
        const float4* xp = (const float4*)(in + (size_t)b * 64);
#pragma unroll
        for (int q = 0; q < 16; ++q) {
            float4 a = xp[q];
            x[q * 4 + 0] = a.x; x[q * 4 + 1] = a.y;
            x[q * 4 + 2] = a.z; x[q * 4 + 3] = a.w;
        }
    }

    float h0[16], c0[16], h1[16], c1[16];
#pragma unroll
    for (int j = 0; j < 16; ++j) { h0[j] = 0.f; c0[j] = 0.f; h1[j] = 0.f; c1[j] = 0.f; }

#pragma unroll
    for (int t = 0; t < 8; ++t) {
        float xt[8];
#pragma unroll
        for (int k = 0; k < 8; ++k) xt[k] = x[t * 8 + k];

        // layer 0
        float nh[16];
        lstm_cell<8>(Wih0, Whh0, bih0, bhh0, xt, h0, c0, nh);
#pragma unroll
        for (int j = 0; j < 16; ++j) h0[j] = nh[j];

        // layer 1 (consumes fresh h0)
        float nh1[16];
        lstm_cell<16>(Wih1, Whh1, bih1, bhh1, h0, h1, c1, nh1);
#pragma unroll
        for (int j = 0; j < 16; ++j) h1[j] = nh1[j];
    }

    // FC on last h1: 10 outputs, 40B contiguous per thread.
    float r[10];
#pragma unroll
    for (int ci = 0; ci < 10; ++ci) {
        float acc = bfc[ci];
#pragma unroll
        for (int k = 0; k < 16; ++k) acc += Wfc[ci * 16 + k] * h1[k];
        r[ci] = acc;
    }
    float* op = out + (size_t)b * 10;
#pragma unroll
    for (int ci = 0; ci < 10; ++ci) op[ci] = r[ci];
}

extern "C" void kernel_launch(void* const* d_in, const int* in_sizes, int n_in,
                              void* d_out, int out_size, void* d_ws, size_t ws_size,
                              hipStream_t stream) {
    const float* in   = (const float*)d_in[0];
    const float* Wih0 = (const float*)d_in[1];
    const float* Whh0 = (const float*)d_in[2];
    const float* bih0 = (const float*)d_in[3];
    const float* bhh0 = (const float*)d_in[4];
    const float* Wih1 = (const float*)d_in[5];
    const float* Whh1 = (const float*)d_in[6];
    const float* bih1 = (const float*)d_in[7];
    const float* bhh1 = (const float*)d_in[8];
    const float* Wfc  = (const float*)d_in[9];
    const float* bfc  = (const float*)d_in[10];
    float* out = (float*)d_out;

    int B = in_sizes[0] / 64;   // 262144
    int block = 256;
    int grid = (B + block - 1) / block;
    lstm_fused_kernel<<<grid, block, 0, stream>>>(in, Wih0, Whh0, bih0, bhh0,
                                                  Wih1, Whh1, bih1, bhh1,
                                                  Wfc, bfc, out, B);
}